// Round 1
// baseline (1562.392 us; speedup 1.0000x reference)
//
#include <hip/hip_runtime.h>
#include <cstdint>
#include <cstddef>

#define Bv 4
#define Sv 2048
#define Hv 16
#define DKv 64
#define Dv 1024
#define Mv (Bv*Sv)   // 8192

typedef __attribute__((ext_vector_type(8))) short short8;
typedef __attribute__((ext_vector_type(8))) unsigned short ushort8v;
typedef __attribute__((ext_vector_type(4))) float f32x4;

__device__ inline float bf2f(unsigned short u) {
  union { unsigned int i; float f; } x; x.i = ((unsigned int)u) << 16; return x.f;
}
__device__ inline unsigned short f2bf(float f) {
  union { float f; unsigned int i; } x; x.f = f;
  unsigned int r = x.i + 0x7FFFu + ((x.i >> 16) & 1u);
  return (unsigned short)(r >> 16);
}

typedef __attribute__((address_space(1))) const unsigned short gu16;
typedef __attribute__((address_space(3))) unsigned short lu16;
__device__ inline void gld_lds16(const unsigned short* g, unsigned short* l) {
  __builtin_amdgcn_global_load_lds((gu16*)g, (lu16*)l, 16, 0, 0);
}

// ---------------- fp32 -> bf16 convert (vectorized, G13) ----------------
__global__ __launch_bounds__(256) void cvt_f32_bf16(const float* __restrict__ src,
                                                    unsigned short* __restrict__ dst, int n4) {
  int i = blockIdx.x * 256 + threadIdx.x;
  if (i >= n4) return;
  float4 v = reinterpret_cast<const float4*>(src)[i];
  ushort4 o;
  o.x = f2bf(v.x); o.y = f2bf(v.y); o.z = f2bf(v.z); o.w = f2bf(v.w);
  reinterpret_cast<ushort4*>(dst)[i] = o;
}

// ---------------- RoPE cos/sin table: tab[s][0:32]=cos, tab[s][32:64]=sin ----------------
__global__ __launch_bounds__(256) void rope_table_k(const int* __restrict__ pos,
                                                    float* __restrict__ tab) {
  int idx = blockIdx.x * 256 + threadIdx.x;  // Sv*32
  int s = idx >> 5, i = idx & 31;
  float p = (float)pos[s];
  // inv_freq = theta^(-i/32) = 2^(-i*log2(10000)/32)
  float a = p * __builtin_exp2f(-0.41524101186092027f * (float)i);
  tab[(s << 6) + i]      = __builtin_cosf(a);
  tab[(s << 6) + 32 + i] = __builtin_sinf(a);
}

// ---------------- in-place RoPE on bf16 [B,S,H*64], interleaved pairs ----------------
__global__ __launch_bounds__(256) void rope_apply_k(unsigned short* __restrict__ T,
                                                    const float* __restrict__ tab) {
  int p = blockIdx.x * 256 + threadIdx.x;  // Bv*Sv*Hv*32
  int i = p & 31;
  int h = (p >> 5) & (Hv - 1);
  int s = (p >> 9) & (Sv - 1);
  int b = p >> 20;
  size_t addr = ((size_t)(b * Sv + s)) * Dv + h * 64 + 2 * i;
  ushort2 u = *reinterpret_cast<ushort2*>(&T[addr]);
  float c  = tab[(s << 6) + i];
  float sn = tab[(s << 6) + 32 + i];
  float x0 = bf2f(u.x), x1 = bf2f(u.y);
  ushort2 o;
  o.x = f2bf(x0 * c - x1 * sn);
  o.y = f2bf(x0 * sn + x1 * c);
  *reinterpret_cast<ushort2*>(&T[addr]) = o;
}

// ---------------- bf16 GEMM: C[M,N] = A[M,K] * B[N,K]^T  (m97 structure) ----------------
__device__ inline void storeC(float* p, float v) { *p = v; }
__device__ inline void storeC(unsigned short* p, float v) { *p = f2bf(v); }

template <typename CT>
__global__ __launch_bounds__(256) void gemm_bt_128(
    const unsigned short* __restrict__ A,  // [M,K] bf16
    const unsigned short* __restrict__ B,  // [N,K] bf16 (weights [out,in])
    CT* __restrict__ C,                    // [M,N]
    int M, int N, int K) {
  __shared__ unsigned short As[128 * 32];
  __shared__ unsigned short Bs[128 * 32];
  const int tid = threadIdx.x;
  const int wave = tid >> 6, lane = tid & 63;
  const int bm = blockIdx.y * 128, bn = blockIdx.x * 128;
  const int wr = (wave >> 1) * 64, wc = (wave & 1) * 64;

  f32x4 acc[4][4] = {};

  // staging: chunk c covers LDS bytes [c*1024, c*1024+1024), linear (gload_lds: dest = base + lane*16)
  const int c0 = wave * 2, c1 = c0 + 1;
  const int sr0 = c0 * 16 + (lane >> 2);
  const int sr1 = c1 * 16 + (lane >> 2);
  const int scol = (lane & 3) * 8;

  const unsigned short* gA0 = A + (size_t)(bm + sr0) * K + scol;
  const unsigned short* gA1 = A + (size_t)(bm + sr1) * K + scol;
  const unsigned short* gB0 = B + (size_t)(bn + sr0) * K + scol;
  const unsigned short* gB1 = B + (size_t)(bn + sr1) * K + scol;
  unsigned short* lA0 = &As[c0 * 512];
  unsigned short* lA1 = &As[c1 * 512];
  unsigned short* lB0 = &Bs[c0 * 512];
  unsigned short* lB1 = &Bs[c1 * 512];

  const int fr = lane & 15;          // row/col within 16x16 fragment
  const int fk = (lane >> 4) * 8;    // k-offset within K=32

  for (int k0 = 0; k0 < K; k0 += 32) {
    gld_lds16(gA0 + k0, lA0);
    gld_lds16(gA1 + k0, lA1);
    gld_lds16(gB0 + k0, lB0);
    gld_lds16(gB1 + k0, lB1);
    __syncthreads();   // compiler drains vmcnt before s_barrier
    short8 af[4], bfr[4];
#pragma unroll
    for (int m = 0; m < 4; m++)
      af[m] = *reinterpret_cast<const short8*>(&As[(wr + m * 16 + fr) * 32 + fk]);
#pragma unroll
    for (int n = 0; n < 4; n++)
      bfr[n] = *reinterpret_cast<const short8*>(&Bs[(wc + n * 16 + fr) * 32 + fk]);
#pragma unroll
    for (int m = 0; m < 4; m++)
#pragma unroll
      for (int n = 0; n < 4; n++)
        acc[m][n] = __builtin_amdgcn_mfma_f32_16x16x32_bf16(af[m], bfr[n], acc[m][n], 0, 0, 0);
    __syncthreads();
  }

  // C/D layout: col = lane&15, row = (lane>>4)*4 + reg   [measured m89/m91]
  const int er = (lane >> 4) * 4, ec = lane & 15;
#pragma unroll
  for (int m = 0; m < 4; m++)
#pragma unroll
    for (int n = 0; n < 4; n++)
#pragma unroll
      for (int r = 0; r < 4; r++) {
        int row = bm + wr + m * 16 + er + r;
        int col = bn + wc + n * 16 + ec;
        storeC(&C[(size_t)row * N + col], acc[m][n][r]);
      }
}

// ---------------- vector-fp32 flash attention (causal), lane=k for scores, lane=d for PV ----
__global__ __launch_bounds__(256) void attn_fwd(
    const unsigned short* __restrict__ Q,
    const unsigned short* __restrict__ K,
    const unsigned short* __restrict__ V,
    unsigned short* __restrict__ O) {
  __shared__ float Ks[64][65];   // +1 pad: conflict-free column reads
  __shared__ float Vs[64][65];
  __shared__ float q_lds[4][64][4];  // [wave][d][qi]
  __shared__ float p_lds[4][64][4];  // [wave][k_local][qi]

  const int tid = threadIdx.x, wave = tid >> 6, lane = tid & 63;
  const int bh = blockIdx.y, b = bh >> 4, h = bh & 15;
  const int q0 = blockIdx.x * 16 + wave * 4;  // 4 q-rows per wave
  const size_t base = ((size_t)b * Sv) * Dv + h * 64;

#pragma unroll
  for (int qi = 0; qi < 4; qi++)
    q_lds[wave][lane][qi] = bf2f(Q[base + (size_t)(q0 + qi) * Dv + lane]);

  float o[4] = {0.f, 0.f, 0.f, 0.f};
  float mrun[4] = {-INFINITY, -INFINITY, -INFINITY, -INFINITY};
  float lrun[4] = {0.f, 0.f, 0.f, 0.f};

  const int ntiles = (blockIdx.x * 16 + 15) / 64 + 1;  // causal: only tiles up to max q

  for (int t = 0; t < ntiles; t++) {
    __syncthreads();  // previous tile's LDS reads done
#pragma unroll
    for (int j = 0; j < 2; j++) {  // stage K,V tile (64x64 bf16 -> fp32 LDS)
      int u = j * 256 + tid;
      int r = u >> 3, cc = (u & 7) * 8;
      size_t g = base + (size_t)(t * 64 + r) * Dv + cc;
      ushort8v kv = *reinterpret_cast<const ushort8v*>(&K[g]);
      ushort8v vv = *reinterpret_cast<const ushort8v*>(&V[g]);
#pragma unroll
      for (int e = 0; e < 8; e++) { Ks[r][cc + e] = bf2f(kv[e]); Vs[r][cc + e] = bf2f(vv[e]); }
    }
    __syncthreads();

    // scores: lane = k-index within tile
    float s0 = 0.f, s1 = 0.f, s2 = 0.f, s3 = 0.f;
#pragma unroll 8
    for (int d = 0; d < 64; d++) {
      float kd = Ks[lane][d];
      f32x4 qv = *reinterpret_cast<const f32x4*>(&q_lds[wave][d][0]);  // broadcast
      s0 = fmaf(qv[0], kd, s0);
      s1 = fmaf(qv[1], kd, s1);
      s2 = fmaf(qv[2], kd, s2);
      s3 = fmaf(qv[3], kd, s3);
    }
    float sarr[4] = {s0, s1, s2, s3};
    const int kk = t * 64 + lane;
#pragma unroll
    for (int qi = 0; qi < 4; qi++) {
      float sv = (kk <= q0 + qi) ? sarr[qi] * 0.125f : -INFINITY;  // 1/sqrt(64)
      float mx = sv;
#pragma unroll
      for (int off = 32; off > 0; off >>= 1) mx = fmaxf(mx, __shfl_xor(mx, off));
      float mn = fmaxf(mrun[qi], mx);
      float sf = __expf(mrun[qi] - mn);  // -inf - finite -> 0 on first tile
      float pp = __expf(sv - mn);
      float ps = pp;
#pragma unroll
      for (int off = 32; off > 0; off >>= 1) ps += __shfl_xor(ps, off);
      lrun[qi] = lrun[qi] * sf + ps;
      o[qi] *= sf;
      mrun[qi] = mn;
      p_lds[wave][lane][qi] = pp;   // wave-private, lockstep => no barrier needed
    }

    // PV: lane = d
#pragma unroll 8
    for (int l = 0; l < 64; l++) {
      float vd = Vs[l][lane];
      f32x4 pv = *reinterpret_cast<const f32x4*>(&p_lds[wave][l][0]);  // broadcast
      o[0] = fmaf(pv[0], vd, o[0]);
      o[1] = fmaf(pv[1], vd, o[1]);
      o[2] = fmaf(pv[2], vd, o[2]);
      o[3] = fmaf(pv[3], vd, o[3]);
    }
  }

#pragma unroll
  for (int qi = 0; qi < 4; qi++)
    O[base + (size_t)(q0 + qi) * Dv + lane] = f2bf(o[qi] / lrun[qi]);
}

// ---------------- launcher ----------------
extern "C" void kernel_launch(void* const* d_in, const int* in_sizes, int n_in,
                              void* d_out, int out_size, void* d_ws, size_t ws_size,
                              hipStream_t stream) {
  const float* x   = (const float*)d_in[0];
  const int*   pos = (const int*)d_in[1];
  const float* wq  = (const float*)d_in[2];
  const float* wk  = (const float*)d_in[3];
  const float* wv  = (const float*)d_in[4];
  const float* wo  = (const float*)d_in[5];
  float* out = (float*)d_out;

  char* w = (char*)d_ws;
  unsigned short* xb  = (unsigned short*)(w);                        // 16 MB, reused as attn out
  unsigned short* wqb = (unsigned short*)(w + (16u << 20));          // 2 MB each
  unsigned short* wkb = (unsigned short*)(w + (18u << 20));
  unsigned short* wvb = (unsigned short*)(w + (20u << 20));
  unsigned short* wob = (unsigned short*)(w + (22u << 20));
  unsigned short* Qp  = (unsigned short*)(w + (24u << 20));          // 16 MB each
  unsigned short* Kp  = (unsigned short*)(w + (40u << 20));
  unsigned short* Vp  = (unsigned short*)(w + (56u << 20));
  float*          tab = (float*)(w + (72u << 20));                   // 512 KB

  cvt_f32_bf16<<<(Mv * Dv / 4) / 256, 256, 0, stream>>>(x, xb, Mv * Dv / 4);
  cvt_f32_bf16<<<(Dv * Dv / 4) / 256, 256, 0, stream>>>(wq, wqb, Dv * Dv / 4);
  cvt_f32_bf16<<<(Dv * Dv / 4) / 256, 256, 0, stream>>>(wk, wkb, Dv * Dv / 4);
  cvt_f32_bf16<<<(Dv * Dv / 4) / 256, 256, 0, stream>>>(wv, wvb, Dv * Dv / 4);
  cvt_f32_bf16<<<(Dv * Dv / 4) / 256, 256, 0, stream>>>(wo, wob, Dv * Dv / 4);
  rope_table_k<<<(Sv * 32) / 256, 256, 0, stream>>>(pos, tab);

  dim3 gg(Dv / 128, Mv / 128);  // (8, 64)
  gemm_bt_128<unsigned short><<<gg, 256, 0, stream>>>(xb, wqb, Qp, Mv, Dv, Dv);
  gemm_bt_128<unsigned short><<<gg, 256, 0, stream>>>(xb, wkb, Kp, Mv, Dv, Dv);
  gemm_bt_128<unsigned short><<<gg, 256, 0, stream>>>(xb, wvb, Vp, Mv, Dv, Dv);

  rope_apply_k<<<(Bv * Sv * Hv * 32) / 256, 256, 0, stream>>>(Qp, tab);
  rope_apply_k<<<(Bv * Sv * Hv * 32) / 256, 256, 0, stream>>>(Kp, tab);

  attn_fwd<<<dim3(Sv / 16, Bv * Hv), 256, 0, stream>>>(Qp, Kp, Vp, xb);

  gemm_bt_128<float><<<gg, 256, 0, stream>>>(xb, wob, out, Mv, Dv, Dv);
}

// Round 2
// 406.181 us; speedup vs baseline: 3.8465x; 3.8465x over previous
//
#include <hip/hip_runtime.h>
#include <cstdint>
#include <cstddef>

#define Bv 4
#define Sv 2048
#define Hv 16
#define Dv 1024
#define Mv (Bv*Sv)   // 8192

typedef __attribute__((ext_vector_type(8))) short short8;
typedef __attribute__((ext_vector_type(8))) unsigned short ushort8v;
typedef __attribute__((ext_vector_type(4))) float f32x4;

__device__ inline float bf2f(unsigned short u) {
  union { unsigned int i; float f; } x; x.i = ((unsigned int)u) << 16; return x.f;
}
__device__ inline unsigned short f2bf(float f) {
  union { float f; unsigned int i; } x; x.f = f;
  unsigned int r = x.i + 0x7FFFu + ((x.i >> 16) & 1u);
  return (unsigned short)(r >> 16);
}

typedef __attribute__((address_space(1))) const unsigned short gu16;
typedef __attribute__((address_space(3))) unsigned short lu16;
__device__ inline void gld_lds16(const unsigned short* g, unsigned short* l) {
  __builtin_amdgcn_global_load_lds((gu16*)g, (lu16*)l, 16, 0, 0);
}

// ---------------- fp32 -> bf16 convert ----------------
__global__ __launch_bounds__(256) void cvt_f32_bf16(const float* __restrict__ src,
                                                    unsigned short* __restrict__ dst, int n4) {
  int i = blockIdx.x * 256 + threadIdx.x;
  if (i >= n4) return;
  float4 v = reinterpret_cast<const float4*>(src)[i];
  ushort4 o;
  o.x = f2bf(v.x); o.y = f2bf(v.y); o.z = f2bf(v.z); o.w = f2bf(v.w);
  reinterpret_cast<ushort4*>(dst)[i] = o;
}

// ---------------- RoPE cos/sin table ----------------
__global__ __launch_bounds__(256) void rope_table_k(const int* __restrict__ pos,
                                                    float* __restrict__ tab) {
  int idx = blockIdx.x * 256 + threadIdx.x;  // Sv*32
  int s = idx >> 5, i = idx & 31;
  float p = (float)pos[s];
  float a = p * __builtin_exp2f(-0.41524101186092027f * (float)i);
  tab[(s << 6) + i]      = __builtin_cosf(a);
  tab[(s << 6) + 32 + i] = __builtin_sinf(a);
}

// ---------------- in-place RoPE on bf16 [B,S,H*64] ----------------
__global__ __launch_bounds__(256) void rope_apply_k(unsigned short* __restrict__ T,
                                                    const float* __restrict__ tab) {
  int p = blockIdx.x * 256 + threadIdx.x;  // Bv*Sv*Hv*32
  int i = p & 31;
  int h = (p >> 5) & (Hv - 1);
  int s = (p >> 9) & (Sv - 1);
  int b = p >> 20;
  size_t addr = ((size_t)(b * Sv + s)) * Dv + h * 64 + 2 * i;
  ushort2 u = *reinterpret_cast<ushort2*>(&T[addr]);
  float c  = tab[(s << 6) + i];
  float sn = tab[(s << 6) + 32 + i];
  float x0 = bf2f(u.x), x1 = bf2f(u.y);
  ushort2 o;
  o.x = f2bf(x0 * c - x1 * sn);
  o.y = f2bf(x0 * sn + x1 * c);
  *reinterpret_cast<ushort2*>(&T[addr]) = o;
}

// ---------------- bf16 GEMM: C[M,N] = A[M,K] * B[N,K]^T (m97 structure) ----------------
__device__ inline void storeC(float* p, float v) { *p = v; }
__device__ inline void storeC(unsigned short* p, float v) { *p = f2bf(v); }

template <typename CT>
__global__ __launch_bounds__(256) void gemm_bt_128(
    const unsigned short* __restrict__ A,
    const unsigned short* __restrict__ B,
    CT* __restrict__ C,
    int M, int N, int K) {
  __shared__ unsigned short As[128 * 32];
  __shared__ unsigned short Bs[128 * 32];
  const int tid = threadIdx.x;
  const int wave = tid >> 6, lane = tid & 63;
  const int bm = blockIdx.y * 128, bn = blockIdx.x * 128;
  const int wr = (wave >> 1) * 64, wc = (wave & 1) * 64;

  f32x4 acc[4][4] = {};

  const int c0 = wave * 2, c1 = c0 + 1;
  const int sr0 = c0 * 16 + (lane >> 2);
  const int sr1 = c1 * 16 + (lane >> 2);
  const int scol = (lane & 3) * 8;

  const unsigned short* gA0 = A + (size_t)(bm + sr0) * K + scol;
  const unsigned short* gA1 = A + (size_t)(bm + sr1) * K + scol;
  const unsigned short* gB0 = B + (size_t)(bn + sr0) * K + scol;
  const unsigned short* gB1 = B + (size_t)(bn + sr1) * K + scol;
  unsigned short* lA0 = &As[c0 * 512];
  unsigned short* lA1 = &As[c1 * 512];
  unsigned short* lB0 = &Bs[c0 * 512];
  unsigned short* lB1 = &Bs[c1 * 512];

  const int fr = lane & 15;
  const int fk = (lane >> 4) * 8;

  for (int k0 = 0; k0 < K; k0 += 32) {
    gld_lds16(gA0 + k0, lA0);
    gld_lds16(gA1 + k0, lA1);
    gld_lds16(gB0 + k0, lB0);
    gld_lds16(gB1 + k0, lB1);
    __syncthreads();
    short8 af[4], bfr[4];
#pragma unroll
    for (int m = 0; m < 4; m++)
      af[m] = *reinterpret_cast<const short8*>(&As[(wr + m * 16 + fr) * 32 + fk]);
#pragma unroll
    for (int n = 0; n < 4; n++)
      bfr[n] = *reinterpret_cast<const short8*>(&Bs[(wc + n * 16 + fr) * 32 + fk]);
#pragma unroll
    for (int m = 0; m < 4; m++)
#pragma unroll
      for (int n = 0; n < 4; n++)
        acc[m][n] = __builtin_amdgcn_mfma_f32_16x16x32_bf16(af[m], bfr[n], acc[m][n], 0, 0, 0);
    __syncthreads();
  }

  const int er = (lane >> 4) * 4, ec = lane & 15;
#pragma unroll
  for (int m = 0; m < 4; m++)
#pragma unroll
    for (int n = 0; n < 4; n++)
#pragma unroll
      for (int r = 0; r < 4; r++) {
        int row = bm + wr + m * 16 + er + r;
        int col = bn + wc + n * 16 + ec;
        storeC(&C[(size_t)row * N + col], acc[m][n][r]);
      }
}

// ---------------- V transpose: V[b,s,h*64+d] -> Vt[(b*16+h)*64+d][s] ----------------
__global__ __launch_bounds__(256) void transpose_v(const unsigned short* __restrict__ V,
                                                   unsigned short* __restrict__ Vt) {
  __shared__ unsigned short Ls[64][72];
  const int tid = threadIdx.x;
  const int s0 = blockIdx.x * 64;
  const int bh = blockIdx.y, b = bh >> 4, h = bh & 15;
  const size_t inbase = ((size_t)b * Sv) * Dv + h * 64;
#pragma unroll
  for (int it = 0; it < 2; ++it) {
    int sl = it * 32 + (tid >> 3);
    int c = (tid & 7) * 8;
    short8 v = *reinterpret_cast<const short8*>(V + inbase + (size_t)(s0 + sl) * Dv + c);
    *reinterpret_cast<short8*>(&Ls[sl][c]) = v;
  }
  __syncthreads();
  const int d = tid >> 2, sc = tid & 3;
#pragma unroll
  for (int k2 = 0; k2 < 2; ++k2) {
    int sbase = sc * 16 + k2 * 8;
    ushort8v o;
#pragma unroll
    for (int j = 0; j < 8; ++j) o[j] = Ls[sbase + j][d];
    *reinterpret_cast<ushort8v*>(Vt + ((size_t)bh * 64 + d) * Sv + s0 + sbase) = o;
  }
}

// ---------------- MFMA flash attention (causal), swapped-QK^T, no LDS ----------------
// Per wave: 32 q-rows. S^T = mfma(K, Q): lane (g=lane>>4, m=lane&15) holds
// S^T[k=16*kf+4g+r][q=m]. PV: O^T = mfma(Vt_rows, P^T); P^T B-frags built via
// ds_bpermute exchange: word t of target (g',m) = pk[2ks+(g'>>1)][t&1] from
// source lane 16*(2(g'&1)+(t>>1)) + m.
__global__ __launch_bounds__(256) void attn_mfma(
    const unsigned short* __restrict__ Q,
    const unsigned short* __restrict__ K,
    const unsigned short* __restrict__ Vt,
    unsigned short* __restrict__ O) {
  const int tid = threadIdx.x;
  const int wave = tid >> 6, lane = tid & 63;
  const int g = lane >> 4, m = lane & 15;
  const int bh = blockIdx.y, b = bh >> 4, h = bh & 15;
  const int q0 = blockIdx.x * 128 + wave * 32;
  const size_t qkbase = ((size_t)b * Sv) * Dv + (size_t)h * 64;
  const size_t vtbase = (size_t)bh * 64 * Sv;
  const f32x4 zf = {0.f, 0.f, 0.f, 0.f};

  short8 qfr[2][2];
#pragma unroll
  for (int qf = 0; qf < 2; ++qf)
#pragma unroll
    for (int ks = 0; ks < 2; ++ks)
      qfr[qf][ks] = *reinterpret_cast<const short8*>(
          Q + qkbase + (size_t)(q0 + qf * 16 + m) * Dv + ks * 32 + g * 8);

  f32x4 oacc[2][4] = {};
  float mrun2[2] = {-INFINITY, -INFINITY};
  float lrun[2] = {0.f, 0.f};

  const int nt = (q0 >> 6) + 1;
  const int idx0 = (((g & 1) << 5) + m) << 2;  // src lane 16*(2(g&1)) + m, bytes
  const int idx1 = idx0 + 64;                  // src lane +16

  for (int t = 0; t < nt; ++t) {
    const int kbase = t << 6;
    f32x4 sacc[2][4];
    short8 kfr[4];
#pragma unroll
    for (int kf = 0; kf < 4; ++kf)
      kfr[kf] = *reinterpret_cast<const short8*>(
          K + qkbase + (size_t)(kbase + kf * 16 + m) * Dv + g * 8);
#pragma unroll
    for (int qf = 0; qf < 2; ++qf)
#pragma unroll
      for (int kf = 0; kf < 4; ++kf)
        sacc[qf][kf] = __builtin_amdgcn_mfma_f32_16x16x32_bf16(kfr[kf], qfr[qf][0], zf, 0, 0, 0);
#pragma unroll
    for (int kf = 0; kf < 4; ++kf)
      kfr[kf] = *reinterpret_cast<const short8*>(
          K + qkbase + (size_t)(kbase + kf * 16 + m) * Dv + 32 + g * 8);
#pragma unroll
    for (int qf = 0; qf < 2; ++qf)
#pragma unroll
      for (int kf = 0; kf < 4; ++kf)
        sacc[qf][kf] = __builtin_amdgcn_mfma_f32_16x16x32_bf16(kfr[kf], qfr[qf][1], sacc[qf][kf], 0, 0, 0);

    const bool lastt = (t == nt - 1);
    unsigned int pk[2][4][2];
    float sf[2];
#pragma unroll
    for (int qf = 0; qf < 2; ++qf) {
      const int qrel = q0 + qf * 16 + m - kbase - 4 * g;
      float pv[4][4];
      float mx = -INFINITY;
#pragma unroll
      for (int kf = 0; kf < 4; ++kf)
#pragma unroll
        for (int r = 0; r < 4; ++r) {
          float s = sacc[qf][kf][r];
          if (lastt) s = (kf * 16 + r > qrel) ? -INFINITY : s;
          pv[kf][r] = s;
          mx = fmaxf(mx, s);
        }
      mx = fmaxf(mx, __shfl_xor(mx, 16));
      mx = fmaxf(mx, __shfl_xor(mx, 32));
      const float c1 = 0.18033688011112042f;  // log2(e)/8  (scale = 1/sqrt(64))
      float m2 = fmaxf(mrun2[qf], mx * c1);
      float sfq = __builtin_exp2f(mrun2[qf] - m2);  // first tile: exp2(-inf)=0
      float ps = 0.f;
#pragma unroll
      for (int kf = 0; kf < 4; ++kf)
#pragma unroll
        for (int r = 0; r < 4; ++r) {
          float p = __builtin_exp2f(__builtin_fmaf(pv[kf][r], c1, -m2));
          ps += p;
          pv[kf][r] = p;
        }
      ps += __shfl_xor(ps, 16);
      ps += __shfl_xor(ps, 32);
      lrun[qf] = lrun[qf] * sfq + ps;
      mrun2[qf] = m2;
      sf[qf] = sfq;
#pragma unroll
      for (int kf = 0; kf < 4; ++kf)
#pragma unroll
        for (int hh = 0; hh < 2; ++hh)
          pk[qf][kf][hh] = (unsigned int)f2bf(pv[kf][2 * hh]) |
                           ((unsigned int)f2bf(pv[kf][2 * hh + 1]) << 16);
    }
#pragma unroll
    for (int qf = 0; qf < 2; ++qf)
#pragma unroll
      for (int dc = 0; dc < 4; ++dc)
#pragma unroll
        for (int r = 0; r < 4; ++r)
          oacc[qf][dc][r] *= sf[qf];

#pragma unroll
    for (int ks = 0; ks < 2; ++ks) {
      short8 vfr[4];
#pragma unroll
      for (int dc = 0; dc < 4; ++dc)
        vfr[dc] = *reinterpret_cast<const short8*>(
            Vt + vtbase + (size_t)(dc * 16 + m) * Sv + kbase + ks * 32 + g * 8);
#pragma unroll
      for (int qf = 0; qf < 2; ++qf) {
        int ra = __builtin_amdgcn_ds_bpermute(idx0, (int)pk[qf][2 * ks][0]);
        int rb = __builtin_amdgcn_ds_bpermute(idx0, (int)pk[qf][2 * ks + 1][0]);
        int rc = __builtin_amdgcn_ds_bpermute(idx0, (int)pk[qf][2 * ks][1]);
        int rd = __builtin_amdgcn_ds_bpermute(idx0, (int)pk[qf][2 * ks + 1][1]);
        int re = __builtin_amdgcn_ds_bpermute(idx1, (int)pk[qf][2 * ks][0]);
        int rf = __builtin_amdgcn_ds_bpermute(idx1, (int)pk[qf][2 * ks + 1][0]);
        int rg = __builtin_amdgcn_ds_bpermute(idx1, (int)pk[qf][2 * ks][1]);
        int rh = __builtin_amdgcn_ds_bpermute(idx1, (int)pk[qf][2 * ks + 1][1]);
        const bool hi = (g >= 2);
        union { unsigned int u[4]; short8 v; } pw;
        pw.u[0] = hi ? (unsigned)rb : (unsigned)ra;
        pw.u[1] = hi ? (unsigned)rd : (unsigned)rc;
        pw.u[2] = hi ? (unsigned)rf : (unsigned)re;
        pw.u[3] = hi ? (unsigned)rh : (unsigned)rg;
#pragma unroll
        for (int dc = 0; dc < 4; ++dc)
          oacc[qf][dc] = __builtin_amdgcn_mfma_f32_16x16x32_bf16(vfr[dc], pw.v, oacc[qf][dc], 0, 0, 0);
      }
    }
  }

#pragma unroll
  for (int qf = 0; qf < 2; ++qf) {
    float rn = 1.0f / lrun[qf];
    size_t row = (size_t)(q0 + qf * 16 + m);
#pragma unroll
    for (int dc = 0; dc < 4; ++dc) {
      ushort4 ov;
      ov.x = f2bf(oacc[qf][dc][0] * rn);
      ov.y = f2bf(oacc[qf][dc][1] * rn);
      ov.z = f2bf(oacc[qf][dc][2] * rn);
      ov.w = f2bf(oacc[qf][dc][3] * rn);
      *reinterpret_cast<ushort4*>(O + qkbase + row * Dv + dc * 16 + 4 * g) = ov;
    }
  }
}

// ---------------- launcher ----------------
extern "C" void kernel_launch(void* const* d_in, const int* in_sizes, int n_in,
                              void* d_out, int out_size, void* d_ws, size_t ws_size,
                              hipStream_t stream) {
  const float* x   = (const float*)d_in[0];
  const int*   pos = (const int*)d_in[1];
  const float* wq  = (const float*)d_in[2];
  const float* wk  = (const float*)d_in[3];
  const float* wv  = (const float*)d_in[4];
  const float* wo  = (const float*)d_in[5];
  float* out = (float*)d_out;

  char* w = (char*)d_ws;
  unsigned short* xb  = (unsigned short*)(w);               // 16 MB: x bf16, later Vt
  unsigned short* wqb = (unsigned short*)(w + (16u << 20));
  unsigned short* wkb = (unsigned short*)(w + (18u << 20));
  unsigned short* wvb = (unsigned short*)(w + (20u << 20));
  unsigned short* wob = (unsigned short*)(w + (22u << 20));
  unsigned short* Qp  = (unsigned short*)(w + (24u << 20));  // 16 MB
  unsigned short* Kp  = (unsigned short*)(w + (40u << 20));  // 16 MB
  unsigned short* Vp  = (unsigned short*)(w + (56u << 20));  // 16 MB: V, later attn out
  float*          tab = (float*)(w + (72u << 20));           // 512 KB

  cvt_f32_bf16<<<(Mv * Dv / 4) / 256, 256, 0, stream>>>(x, xb, Mv * Dv / 4);
  cvt_f32_bf16<<<(Dv * Dv / 4) / 256, 256, 0, stream>>>(wq, wqb, Dv * Dv / 4);
  cvt_f32_bf16<<<(Dv * Dv / 4) / 256, 256, 0, stream>>>(wk, wkb, Dv * Dv / 4);
  cvt_f32_bf16<<<(Dv * Dv / 4) / 256, 256, 0, stream>>>(wv, wvb, Dv * Dv / 4);
  cvt_f32_bf16<<<(Dv * Dv / 4) / 256, 256, 0, stream>>>(wo, wob, Dv * Dv / 4);
  rope_table_k<<<(Sv * 32) / 256, 256, 0, stream>>>(pos, tab);

  dim3 gg(Dv / 128, Mv / 128);  // (8, 64)
  gemm_bt_128<unsigned short><<<gg, 256, 0, stream>>>(xb, wqb, Qp, Mv, Dv, Dv);
  gemm_bt_128<unsigned short><<<gg, 256, 0, stream>>>(xb, wkb, Kp, Mv, Dv, Dv);
  gemm_bt_128<unsigned short><<<gg, 256, 0, stream>>>(xb, wvb, Vp, Mv, Dv, Dv);

  // xb (x bf16) is dead after the three GEMMs; reuse as Vt.
  transpose_v<<<dim3(Sv / 64, Bv * Hv), 256, 0, stream>>>(Vp, xb);

  rope_apply_k<<<(Bv * Sv * Hv * 32) / 256, 256, 0, stream>>>(Qp, tab);
  rope_apply_k<<<(Bv * Sv * Hv * 32) / 256, 256, 0, stream>>>(Kp, tab);

  // attn out -> Vp region (raw V dead after transpose)
  attn_mfma<<<dim3(Sv / 128, Bv * Hv), 256, 0, stream>>>(Qp, Kp, xb, Vp);

  gemm_bt_128<float><<<gg, 256, 0, stream>>>(Vp, wob, out, Mv, Dv, Dv);
}

// Round 3
// 305.127 us; speedup vs baseline: 5.1205x; 1.3312x over previous
//
#include <hip/hip_runtime.h>
#include <cstdint>
#include <cstddef>

#define Bv 4
#define Sv 2048
#define Hv 16
#define Dv 1024
#define Mv (Bv*Sv)   // 8192

typedef __attribute__((ext_vector_type(8))) short short8;
typedef __attribute__((ext_vector_type(8))) unsigned short ushort8v;
typedef __attribute__((ext_vector_type(4))) float f32x4;

__device__ inline float bf2f(unsigned short u) {
  union { unsigned int i; float f; } x; x.i = ((unsigned int)u) << 16; return x.f;
}
__device__ inline unsigned short f2bf(float f) {
  union { float f; unsigned int i; } x; x.f = f;
  unsigned int r = x.i + 0x7FFFu + ((x.i >> 16) & 1u);
  return (unsigned short)(r >> 16);
}

typedef __attribute__((address_space(1))) const unsigned short gu16;
typedef __attribute__((address_space(3))) unsigned short lu16;
__device__ inline void gld_lds16(const unsigned short* g, unsigned short* l) {
  __builtin_amdgcn_global_load_lds((gu16*)g, (lu16*)l, 16, 0, 0);
}

// ---------------- fp32 -> bf16 convert ----------------
__global__ __launch_bounds__(256) void cvt_f32_bf16(const float* __restrict__ src,
                                                    unsigned short* __restrict__ dst, int n4) {
  int i = blockIdx.x * 256 + threadIdx.x;
  if (i >= n4) return;
  float4 v = reinterpret_cast<const float4*>(src)[i];
  ushort4 o;
  o.x = f2bf(v.x); o.y = f2bf(v.y); o.z = f2bf(v.z); o.w = f2bf(v.w);
  reinterpret_cast<ushort4*>(dst)[i] = o;
}

// ---------------- RoPE cos/sin table ----------------
__global__ __launch_bounds__(256) void rope_table_k(const int* __restrict__ pos,
                                                    float* __restrict__ tab) {
  int idx = blockIdx.x * 256 + threadIdx.x;  // Sv*32
  int s = idx >> 5, i = idx & 31;
  float p = (float)pos[s];
  float a = p * __builtin_exp2f(-0.41524101186092027f * (float)i);
  tab[(s << 6) + i]      = __builtin_cosf(a);
  tab[(s << 6) + 32 + i] = __builtin_sinf(a);
}

// ---------------- in-place RoPE on bf16 [B,S,H*64] ----------------
__global__ __launch_bounds__(256) void rope_apply_k(unsigned short* __restrict__ T,
                                                    const float* __restrict__ tab) {
  int p = blockIdx.x * 256 + threadIdx.x;  // Bv*Sv*Hv*32
  int i = p & 31;
  int h = (p >> 5) & (Hv - 1);
  int s = (p >> 9) & (Sv - 1);
  int b = p >> 20;
  size_t addr = ((size_t)(b * Sv + s)) * Dv + h * 64 + 2 * i;
  ushort2 u = *reinterpret_cast<ushort2*>(&T[addr]);
  float c  = tab[(s << 6) + i];
  float sn = tab[(s << 6) + 32 + i];
  float x0 = bf2f(u.x), x1 = bf2f(u.y);
  ushort2 o;
  o.x = f2bf(x0 * c - x1 * sn);
  o.y = f2bf(x0 * sn + x1 * c);
  *reinterpret_cast<ushort2*>(&T[addr]) = o;
}

// ---------------- bf16 GEMM: C[M,N] = A[M,K] * B[N,K]^T (m97 structure) ----------------
__device__ inline void storeC(float* p, float v) { *p = v; }
__device__ inline void storeC(unsigned short* p, float v) { *p = f2bf(v); }

template <typename CT>
__global__ __launch_bounds__(256) void gemm_bt_128(
    const unsigned short* __restrict__ A,
    const unsigned short* __restrict__ B,
    CT* __restrict__ C,
    int M, int N, int K) {
  __shared__ unsigned short As[128 * 32];
  __shared__ unsigned short Bs[128 * 32];
  const int tid = threadIdx.x;
  const int wave = tid >> 6, lane = tid & 63;
  const int bm = blockIdx.y * 128, bn = blockIdx.x * 128;
  const int wr = (wave >> 1) * 64, wc = (wave & 1) * 64;

  f32x4 acc[4][4] = {};

  const int c0 = wave * 2, c1 = c0 + 1;
  const int sr0 = c0 * 16 + (lane >> 2);
  const int sr1 = c1 * 16 + (lane >> 2);
  const int scol = (lane & 3) * 8;

  const unsigned short* gA0 = A + (size_t)(bm + sr0) * K + scol;
  const unsigned short* gA1 = A + (size_t)(bm + sr1) * K + scol;
  const unsigned short* gB0 = B + (size_t)(bn + sr0) * K + scol;
  const unsigned short* gB1 = B + (size_t)(bn + sr1) * K + scol;
  unsigned short* lA0 = &As[c0 * 512];
  unsigned short* lA1 = &As[c1 * 512];
  unsigned short* lB0 = &Bs[c0 * 512];
  unsigned short* lB1 = &Bs[c1 * 512];

  const int fr = lane & 15;
  const int fk = (lane >> 4) * 8;

  for (int k0 = 0; k0 < K; k0 += 32) {
    gld_lds16(gA0 + k0, lA0);
    gld_lds16(gA1 + k0, lA1);
    gld_lds16(gB0 + k0, lB0);
    gld_lds16(gB1 + k0, lB1);
    __syncthreads();
    short8 af[4], bfr[4];
#pragma unroll
    for (int m = 0; m < 4; m++)
      af[m] = *reinterpret_cast<const short8*>(&As[(wr + m * 16 + fr) * 32 + fk]);
#pragma unroll
    for (int n = 0; n < 4; n++)
      bfr[n] = *reinterpret_cast<const short8*>(&Bs[(wc + n * 16 + fr) * 32 + fk]);
#pragma unroll
    for (int m = 0; m < 4; m++)
#pragma unroll
      for (int n = 0; n < 4; n++)
        acc[m][n] = __builtin_amdgcn_mfma_f32_16x16x32_bf16(af[m], bfr[n], acc[m][n], 0, 0, 0);
    __syncthreads();
  }

  const int er = (lane >> 4) * 4, ec = lane & 15;
#pragma unroll
  for (int m = 0; m < 4; m++)
#pragma unroll
    for (int n = 0; n < 4; n++)
#pragma unroll
      for (int r = 0; r < 4; r++) {
        int row = bm + wr + m * 16 + er + r;
        int col = bn + wc + n * 16 + ec;
        storeC(&C[(size_t)row * N + col], acc[m][n][r]);
      }
}

// ---------------- V transpose: V[b,s,h*64+d] -> Vt[(b*16+h)*64+d][s] ----------------
__global__ __launch_bounds__(256) void transpose_v(const unsigned short* __restrict__ V,
                                                   unsigned short* __restrict__ Vt) {
  __shared__ unsigned short Ls[64][72];
  const int tid = threadIdx.x;
  const int s0 = blockIdx.x * 64;
  const int bh = blockIdx.y, b = bh >> 4, h = bh & 15;
  const size_t inbase = ((size_t)b * Sv) * Dv + h * 64;
#pragma unroll
  for (int it = 0; it < 2; ++it) {
    int sl = it * 32 + (tid >> 3);
    int c = (tid & 7) * 8;
    short8 v = *reinterpret_cast<const short8*>(V + inbase + (size_t)(s0 + sl) * Dv + c);
    *reinterpret_cast<short8*>(&Ls[sl][c]) = v;
  }
  __syncthreads();
  const int d = tid >> 2, sc = tid & 3;
#pragma unroll
  for (int k2 = 0; k2 < 2; ++k2) {
    int sbase = sc * 16 + k2 * 8;
    ushort8v o;
#pragma unroll
    for (int j = 0; j < 8; ++j) o[j] = Ls[sbase + j][d];
    *reinterpret_cast<ushort8v*>(Vt + ((size_t)bh * 64 + d) * Sv + s0 + sbase) = o;
  }
}

// ---------------- MFMA flash attention helpers ----------------
// S^T layout per strip: lane (g=lane>>4, m=lane&15) holds S^T[k=16*kf+4g+r][q=qf*16+m].
__device__ __forceinline__ void softmax_strip(
    f32x4 (&sacc)[2][4], const bool lastt, const int qrel0,
    float (&mrun2)[2], float (&lrun)[2], f32x4 (&oacc)[2][4],
    unsigned int (&pk)[2][4][2]) {
  const float c1 = 0.18033688011112042f;  // log2(e)/8  (scale = 1/sqrt(64))
#pragma unroll
  for (int qf = 0; qf < 2; ++qf) {
    const int qrel = qrel0 + qf * 16;
    float pv[4][4];
    float mx = -INFINITY;
#pragma unroll
    for (int kf = 0; kf < 4; ++kf)
#pragma unroll
      for (int r = 0; r < 4; ++r) {
        float s = sacc[qf][kf][r];
        if (lastt) s = (kf * 16 + r > qrel) ? -INFINITY : s;
        pv[kf][r] = s;
        mx = fmaxf(mx, s);
      }
    mx = fmaxf(mx, __shfl_xor(mx, 16));
    mx = fmaxf(mx, __shfl_xor(mx, 32));
    float pm = mx * c1;
    // defer-max (T13): only rescale when the running max grew by > 8 (log2)
    if (__any(pm > mrun2[qf] + 8.0f)) {
      float m2 = fmaxf(mrun2[qf], pm);
      float sfq = __builtin_exp2f(mrun2[qf] - m2);  // first tile: exp2(-inf)=0
      lrun[qf] *= sfq;
#pragma unroll
      for (int dc = 0; dc < 4; ++dc)
#pragma unroll
        for (int r = 0; r < 4; ++r) oacc[qf][dc][r] *= sfq;
      mrun2[qf] = m2;
    }
    const float nm = -mrun2[qf];
    float ps = 0.f;
#pragma unroll
    for (int kf = 0; kf < 4; ++kf)
#pragma unroll
      for (int r = 0; r < 4; ++r) {
        float p = __builtin_exp2f(__builtin_fmaf(pv[kf][r], c1, nm));
        ps += p;
        pv[kf][r] = p;
      }
    ps += __shfl_xor(ps, 16);
    ps += __shfl_xor(ps, 32);
    lrun[qf] += ps;
    // pack P to bf16 pairs with the HW packed convert (T12 recipe)
#pragma unroll
    for (int kf = 0; kf < 4; ++kf)
#pragma unroll
      for (int hh = 0; hh < 2; ++hh) {
        unsigned int rr;
        asm("v_cvt_pk_bf16_f32 %0, %1, %2"
            : "=v"(rr) : "v"(pv[kf][2 * hh]), "v"(pv[kf][2 * hh + 1]));
        pk[qf][kf][hh] = rr;
      }
  }
}

// P^T B-frags built via ds_bpermute: word t of target (g',m) = pk[2ks+(g'>>1)][t&1]
// from source lane 16*(2(g'&1)+(t>>1)) + m.
__device__ __forceinline__ void pv_strip(
    const short8 (&vfr)[2][4], const unsigned int (&pk)[2][4][2],
    f32x4 (&oacc)[2][4], const int idx0, const int idx1, const bool hi) {
#pragma unroll
  for (int ks = 0; ks < 2; ++ks)
#pragma unroll
    for (int qf = 0; qf < 2; ++qf) {
      int ra = __builtin_amdgcn_ds_bpermute(idx0, (int)pk[qf][2 * ks][0]);
      int rb = __builtin_amdgcn_ds_bpermute(idx0, (int)pk[qf][2 * ks + 1][0]);
      int rc = __builtin_amdgcn_ds_bpermute(idx0, (int)pk[qf][2 * ks][1]);
      int rd = __builtin_amdgcn_ds_bpermute(idx0, (int)pk[qf][2 * ks + 1][1]);
      int re = __builtin_amdgcn_ds_bpermute(idx1, (int)pk[qf][2 * ks][0]);
      int rf = __builtin_amdgcn_ds_bpermute(idx1, (int)pk[qf][2 * ks + 1][0]);
      int rg = __builtin_amdgcn_ds_bpermute(idx1, (int)pk[qf][2 * ks][1]);
      int rh = __builtin_amdgcn_ds_bpermute(idx1, (int)pk[qf][2 * ks + 1][1]);
      union { unsigned int u[4]; short8 v; } pw;
      pw.u[0] = hi ? (unsigned)rb : (unsigned)ra;
      pw.u[1] = hi ? (unsigned)rd : (unsigned)rc;
      pw.u[2] = hi ? (unsigned)rf : (unsigned)re;
      pw.u[3] = hi ? (unsigned)rh : (unsigned)rg;
#pragma unroll
      for (int dc = 0; dc < 4; ++dc)
        oacc[qf][dc] = __builtin_amdgcn_mfma_f32_16x16x32_bf16(vfr[ks][dc], pw.v, oacc[qf][dc], 0, 0, 0);
    }
}

// ---------------- MFMA flash attention (causal), paired strips for balance ----------
// Wave owns strips j and 63-j (32 q-rows each): constant 33 tile-units per wave,
// K/V fragment loads shared between the two strips.
__global__ __launch_bounds__(256, 2) void attn_mfma(
    const unsigned short* __restrict__ Q,
    const unsigned short* __restrict__ K,
    const unsigned short* __restrict__ Vt,
    unsigned short* __restrict__ O) {
  const int tid = threadIdx.x;
  const int wave = tid >> 6, lane = tid & 63;
  const int g = lane >> 4, m = lane & 15;
  const int bh = blockIdx.y, b = bh >> 4, h = bh & 15;
  const int j = blockIdx.x * 4 + wave;       // 0..31
  const int sA = j, sB = 63 - j;
  const int qA0 = sA * 32, qB0 = sB * 32;
  const int ntA = (sA >> 1) + 1, ntB = (sB >> 1) + 1;  // ntB > ntA always
  const size_t qkbase = ((size_t)b * Sv) * Dv + (size_t)h * 64;
  const size_t vtbase = (size_t)bh * 64 * Sv;
  const f32x4 zf = {0.f, 0.f, 0.f, 0.f};

  short8 qA[2][2], qB[2][2];
#pragma unroll
  for (int qf = 0; qf < 2; ++qf)
#pragma unroll
    for (int ks = 0; ks < 2; ++ks) {
      qA[qf][ks] = *reinterpret_cast<const short8*>(
          Q + qkbase + (size_t)(qA0 + qf * 16 + m) * Dv + ks * 32 + g * 8);
      qB[qf][ks] = *reinterpret_cast<const short8*>(
          Q + qkbase + (size_t)(qB0 + qf * 16 + m) * Dv + ks * 32 + g * 8);
    }

  const unsigned short* kp[4];
  const unsigned short* vp[4];
#pragma unroll
  for (int kf = 0; kf < 4; ++kf)
    kp[kf] = K + qkbase + (size_t)(kf * 16 + m) * Dv + g * 8;
#pragma unroll
  for (int dc = 0; dc < 4; ++dc)
    vp[dc] = Vt + vtbase + (size_t)(dc * 16 + m) * Sv + g * 8;

  f32x4 oA[2][4] = {}, oB[2][4] = {};
  float mA[2] = {-INFINITY, -INFINITY}, mB[2] = {-INFINITY, -INFINITY};
  float lA[2] = {0.f, 0.f}, lB[2] = {0.f, 0.f};

  const int idx0 = (((g & 1) << 5) + m) << 2;  // src lane 16*(2(g&1)) + m, bytes
  const int idx1 = idx0 + 64;                  // src lane +16
  const bool hi = (g >= 2);
  int qrelA = qA0 + m - 4 * g;
  int qrelB = qB0 + m - 4 * g;

  for (int t = 0; t < ntB; ++t) {
    const bool actA = (t < ntA);
    f32x4 sAacc[2][4], sBacc[2][4];
    short8 kfr[4];
    // --- QK^T, k-half 0 ---
#pragma unroll
    for (int kf = 0; kf < 4; ++kf)
      kfr[kf] = *reinterpret_cast<const short8*>(kp[kf]);
#pragma unroll
    for (int qf = 0; qf < 2; ++qf)
#pragma unroll
      for (int kf = 0; kf < 4; ++kf)
        sBacc[qf][kf] = __builtin_amdgcn_mfma_f32_16x16x32_bf16(kfr[kf], qB[qf][0], zf, 0, 0, 0);
    if (actA)
#pragma unroll
      for (int qf = 0; qf < 2; ++qf)
#pragma unroll
        for (int kf = 0; kf < 4; ++kf)
          sAacc[qf][kf] = __builtin_amdgcn_mfma_f32_16x16x32_bf16(kfr[kf], qA[qf][0], zf, 0, 0, 0);
    // --- QK^T, k-half 1 ---
#pragma unroll
    for (int kf = 0; kf < 4; ++kf)
      kfr[kf] = *reinterpret_cast<const short8*>(kp[kf] + 32);
#pragma unroll
    for (int qf = 0; qf < 2; ++qf)
#pragma unroll
      for (int kf = 0; kf < 4; ++kf)
        sBacc[qf][kf] = __builtin_amdgcn_mfma_f32_16x16x32_bf16(kfr[kf], qB[qf][1], sBacc[qf][kf], 0, 0, 0);
    if (actA)
#pragma unroll
      for (int qf = 0; qf < 2; ++qf)
#pragma unroll
        for (int kf = 0; kf < 4; ++kf)
          sAacc[qf][kf] = __builtin_amdgcn_mfma_f32_16x16x32_bf16(kfr[kf], qA[qf][1], sAacc[qf][kf], 0, 0, 0);

    // --- prefetch V fragments (latency hides under softmax) ---
    short8 vfr[2][4];
#pragma unroll
    for (int ks = 0; ks < 2; ++ks)
#pragma unroll
      for (int dc = 0; dc < 4; ++dc)
        vfr[ks][dc] = *reinterpret_cast<const short8*>(vp[dc] + ks * 32);

    // --- softmax + PV for both strips ---
    unsigned int pkB[2][4][2], pkA[2][4][2];
    softmax_strip(sBacc, t == ntB - 1, qrelB, mB, lB, oB, pkB);
    if (actA) softmax_strip(sAacc, t == ntA - 1, qrelA, mA, lA, oA, pkA);
    pv_strip(vfr, pkB, oB, idx0, idx1, hi);
    if (actA) pv_strip(vfr, pkA, oA, idx0, idx1, hi);

#pragma unroll
    for (int kf = 0; kf < 4; ++kf) kp[kf] += (size_t)64 * Dv;
#pragma unroll
    for (int dc = 0; dc < 4; ++dc) vp[dc] += 64;
    qrelA -= 64; qrelB -= 64;
  }

#pragma unroll
  for (int qf = 0; qf < 2; ++qf) {
    float rnA = 1.0f / lA[qf];
    float rnB = 1.0f / lB[qf];
    size_t rowA = (size_t)(qA0 + qf * 16 + m);
    size_t rowB = (size_t)(qB0 + qf * 16 + m);
#pragma unroll
    for (int dc = 0; dc < 4; ++dc) {
      ushort4 ov;
      ov.x = f2bf(oA[qf][dc][0] * rnA);
      ov.y = f2bf(oA[qf][dc][1] * rnA);
      ov.z = f2bf(oA[qf][dc][2] * rnA);
      ov.w = f2bf(oA[qf][dc][3] * rnA);
      *reinterpret_cast<ushort4*>(O + qkbase + rowA * Dv + dc * 16 + 4 * g) = ov;
      ov.x = f2bf(oB[qf][dc][0] * rnB);
      ov.y = f2bf(oB[qf][dc][1] * rnB);
      ov.z = f2bf(oB[qf][dc][2] * rnB);
      ov.w = f2bf(oB[qf][dc][3] * rnB);
      *reinterpret_cast<ushort4*>(O + qkbase + rowB * Dv + dc * 16 + 4 * g) = ov;
    }
  }
}

// ---------------- launcher ----------------
extern "C" void kernel_launch(void* const* d_in, const int* in_sizes, int n_in,
                              void* d_out, int out_size, void* d_ws, size_t ws_size,
                              hipStream_t stream) {
  const float* x   = (const float*)d_in[0];
  const int*   pos = (const int*)d_in[1];
  const float* wq  = (const float*)d_in[2];
  const float* wk  = (const float*)d_in[3];
  const float* wv  = (const float*)d_in[4];
  const float* wo  = (const float*)d_in[5];
  float* out = (float*)d_out;

  char* w = (char*)d_ws;
  unsigned short* xb  = (unsigned short*)(w);               // 16 MB: x bf16, later Vt
  unsigned short* wqb = (unsigned short*)(w + (16u << 20));
  unsigned short* wkb = (unsigned short*)(w + (18u << 20));
  unsigned short* wvb = (unsigned short*)(w + (20u << 20));
  unsigned short* wob = (unsigned short*)(w + (22u << 20));
  unsigned short* Qp  = (unsigned short*)(w + (24u << 20));  // 16 MB
  unsigned short* Kp  = (unsigned short*)(w + (40u << 20));  // 16 MB
  unsigned short* Vp  = (unsigned short*)(w + (56u << 20));  // 16 MB: V, later attn out
  float*          tab = (float*)(w + (72u << 20));           // 512 KB

  cvt_f32_bf16<<<(Mv * Dv / 4) / 256, 256, 0, stream>>>(x, xb, Mv * Dv / 4);
  cvt_f32_bf16<<<(Dv * Dv / 4) / 256, 256, 0, stream>>>(wq, wqb, Dv * Dv / 4);
  cvt_f32_bf16<<<(Dv * Dv / 4) / 256, 256, 0, stream>>>(wk, wkb, Dv * Dv / 4);
  cvt_f32_bf16<<<(Dv * Dv / 4) / 256, 256, 0, stream>>>(wv, wvb, Dv * Dv / 4);
  cvt_f32_bf16<<<(Dv * Dv / 4) / 256, 256, 0, stream>>>(wo, wob, Dv * Dv / 4);
  rope_table_k<<<(Sv * 32) / 256, 256, 0, stream>>>(pos, tab);

  dim3 gg(Dv / 128, Mv / 128);  // (8, 64)
  gemm_bt_128<unsigned short><<<gg, 256, 0, stream>>>(xb, wqb, Qp, Mv, Dv, Dv);
  gemm_bt_128<unsigned short><<<gg, 256, 0, stream>>>(xb, wkb, Kp, Mv, Dv, Dv);
  gemm_bt_128<unsigned short><<<gg, 256, 0, stream>>>(xb, wvb, Vp, Mv, Dv, Dv);

  // xb (x bf16) is dead after the three GEMMs; reuse as Vt.
  transpose_v<<<dim3(Sv / 64, Bv * Hv), 256, 0, stream>>>(Vp, xb);

  rope_apply_k<<<(Bv * Sv * Hv * 32) / 256, 256, 0, stream>>>(Qp, tab);
  rope_apply_k<<<(Bv * Sv * Hv * 32) / 256, 256, 0, stream>>>(Kp, tab);

  // attn out -> Vp region (raw V dead after transpose)
  attn_mfma<<<dim3(8, Bv * Hv), 256, 0, stream>>>(Qp, Kp, xb, Vp);

  gemm_bt_128<float><<<gg, 256, 0, stream>>>(Vp, wob, out, Mv, Dv, Dv);
}